// Round 7
// baseline (126.307 us; speedup 1.0000x reference)
//
#include <hip/hip_runtime.h>

#define BDIM 512
#define HH 256
#define WW 256
#define NF 64
#define NH 8
#define HW (HH * WW)
#define WBP 68   // padded weight row (bf16 elems): 2-way-free B-frag reads

typedef __attribute__((ext_vector_type(8))) short short8v;
typedef __attribute__((ext_vector_type(4))) float f32x4;

// round-to-nearest-even fp32 -> bf16 bits
__device__ __forceinline__ unsigned short f2bf(float f) {
  const unsigned u = __float_as_uint(f);
  return (unsigned short)((u + 0x7fffu + ((u >> 16) & 1u)) >> 16);
}

// exp2 of 4 fp32 -> packed 2x(2xbf16)
__device__ __forceinline__ uint2 exp2_pack(f32x4 sv) {
  const float e0 = __builtin_amdgcn_exp2f(sv.x);
  const float e1 = __builtin_amdgcn_exp2f(sv.y);
  const float e2 = __builtin_amdgcn_exp2f(sv.z);
  const float e3 = __builtin_amdgcn_exp2f(sv.w);
  uint2 r;
  r.x = (unsigned)f2bf(e0) | ((unsigned)f2bf(e1) << 16);
  r.y = (unsigned)f2bf(e2) | ((unsigned)f2bf(e3) << 16);
  return r;
}

struct __align__(16) Smem {
  unsigned short kb16[WW * 8];     // 4 KB   [u][d]  K bf16
  unsigned short qb16[WW * 8];     // 4 KB   [q][d]  Q bf16, pre-scaled
  unsigned short vb16[8][264];     // 4.125  [d][u]  V bf16 transposed
  union {                          // 10 KB
    struct { unsigned short wb1[16 * WBP]; unsigned short wb2[16 * WBP]; } w;
    float mpst[WW][10];            // [q][ d0..7, l, pad ]  (attention output)
  } u1;
  union {                          // 10 KB
    unsigned short pstage[8][640]; // per-wave P^T staging (attention)
    float murst2[WW][2];           // mu2, rstd2 (projection)
  } u2;
  float murst[WW][2];              // 2 KB  mu1, rstd1 (lives to epilogue)
  float Sq1[NH], Sq0[NH], Sk1[NH], Sk0[NH], Sv1[NH], Sv0[NH], bsel[NH];
};

__global__ __launch_bounds__(BDIM, 8)
void cc_attn_kernel(const float* __restrict__ x1,
                    const float* __restrict__ x2,
                    const float* __restrict__ q_w,
                    const float* __restrict__ q_b,
                    const float* __restrict__ k_w,
                    const float* __restrict__ k_b,
                    const float* __restrict__ v_w,
                    const float* __restrict__ v_b,
                    const float* __restrict__ bias,
                    const float* __restrict__ sel_w,
                    const float* __restrict__ sel_b,
                    const float* __restrict__ fan_w,
                    const float* __restrict__ fan_b,
                    const float* __restrict__ gma,
                    const float* __restrict__ ln1w,
                    const float* __restrict__ ln1b,
                    const float* __restrict__ ln2w,
                    const float* __restrict__ ln2b,
                    float* __restrict__ out)
{
  __shared__ Smem s;
  const int tid  = threadIdx.x;
  const int lane = tid & 63;
  const int wid  = tid >> 6;          // 8 waves
  const int g    = lane >> 4;         // k-octet / row-quad group
  const int r16  = lane & 15;
  const int b = blockIdx.x >> 8;
  const int h = blockIdx.x & 255;
  const size_t rowbase = ((size_t)(b * NF) * HH + h) * WW;

  const float QS = 0.125f * 1.44269504088896340736f;  // SCALE * log2(e)
  const short8v zero8 = {0,0,0,0,0,0,0,0};
  const f32x4 zero4 = {0.f, 0.f, 0.f, 0.f};

  // ---- phase 0a: per-head affine constants (threads 0..7) ----
  if (tid < NH) {
    const int d = tid;
    float s1q = 0, s0q = 0, s1k = 0, s0k = 0, s1v = 0, s0v = 0, bs = 0;
    for (int c = 0; c < NF; c++) {
      const float qw = q_w[d * NF + c], kw = k_w[d * NF + c], vw = v_w[d * NF + c];
      s1q += ln1w[c] * qw; s0q += ln1b[c] * qw;
      s1k += ln2w[c] * kw; s0k += ln2b[c] * kw;
      s1v += ln1w[c] * vw; s0v += ln1b[c] * vw;
      bs  += bias[c] * sel_w[d * NF + c];
    }
    s.Sq1[d] = s1q; s.Sq0[d] = s0q + q_b[d];
    s.Sk1[d] = s1k; s.Sk0[d] = s0k + k_b[d];
    s.Sv1[d] = s1v; s.Sv0[d] = s0v + v_b[d];
    s.bsel[d] = bs + sel_b[d];
  }

  // ---- phase 0b: LN-gain-folded weight matrices, bf16 [n][c] ----
  for (int i = tid; i < 16 * NF; i += BDIM) {
    const int n = i >> 6, c = i & 63;
    const float w1 = (n < 8 ? q_w[n * NF + c] : v_w[(n - 8) * NF + c]) * ln1w[c];
    const float w2 = (n < 8 ? k_w[n * NF + c] * ln2w[c] : 0.f);
    s.u1.w.wb1[n * WBP + c] = f2bf(w1);
    s.u1.w.wb2[n * WBP + c] = f2bf(w2);
  }

  __syncthreads();   // A: weights + consts visible

  // ---- phase 1: projection GEMM via MFMA, register-gathered A-frags ----
  f32x4 accQV0 = zero4, accQV1 = zero4, accK0 = zero4, accK1 = zero4;
  float s1[2] = {0.f, 0.f}, q1[2] = {0.f, 0.f};
  float s2[2] = {0.f, 0.f}, q2p[2] = {0.f, 0.f};

  #pragma unroll 1
  for (int kc = 0; kc < 2; ++kc) {
    const short8v bqv = *reinterpret_cast<const short8v*>(&s.u1.w.wb1[r16 * WBP + kc * 32 + g * 8]);
    const short8v bk  = *reinterpret_cast<const short8v*>(&s.u1.w.wb2[r16 * WBP + kc * 32 + g * 8]);
    #pragma unroll
    for (int m = 0; m < 2; ++m) {
      const int gp = wid * 32 + m * 16 + r16;
      const float* p1 = x1 + rowbase + gp + (size_t)(kc * 32 + g * 8) * HW;
      const float* p2 = x2 + rowbase + gp + (size_t)(kc * 32 + g * 8) * HW;
      float xv[8], yv[8];
      #pragma unroll
      for (int i = 0; i < 8; ++i) xv[i] = p1[(size_t)i * HW];
      #pragma unroll
      for (int i = 0; i < 8; ++i) yv[i] = p2[(size_t)i * HW];
      unsigned short pk1[8], pk2[8];
      float la = 0.f, lb = 0.f, lc = 0.f, ld = 0.f;
      #pragma unroll
      for (int i = 0; i < 8; ++i) {
        la += xv[i]; lb += xv[i] * xv[i]; pk1[i] = f2bf(xv[i]);
        lc += yv[i]; ld += yv[i] * yv[i]; pk2[i] = f2bf(yv[i]);
      }
      s1[m] += la; q1[m] += lb; s2[m] += lc; q2p[m] += ld;
      const short8v a1 = *reinterpret_cast<const short8v*>(pk1);
      const short8v a2 = *reinterpret_cast<const short8v*>(pk2);
      if (m == 0) {
        accQV0 = __builtin_amdgcn_mfma_f32_16x16x32_bf16(a1, bqv, accQV0, 0, 0, 0);
        accK0  = __builtin_amdgcn_mfma_f32_16x16x32_bf16(a2, bk,  accK0,  0, 0, 0);
      } else {
        accQV1 = __builtin_amdgcn_mfma_f32_16x16x32_bf16(a1, bqv, accQV1, 0, 0, 0);
        accK1  = __builtin_amdgcn_mfma_f32_16x16x32_bf16(a2, bk,  accK1,  0, 0, 0);
      }
    }
  }

  // ---- phase 1b: LN stats combine (lane pairs hold complementary octets) ----
  #pragma unroll
  for (int m = 0; m < 2; ++m) {
    float a = s1[m] + __shfl_xor(s1[m], 16);   a += __shfl_xor(a, 32);
    float v = q1[m] + __shfl_xor(q1[m], 16);   v += __shfl_xor(v, 32);
    float c = s2[m] + __shfl_xor(s2[m], 16);   c += __shfl_xor(c, 32);
    float d = q2p[m] + __shfl_xor(q2p[m], 16); d += __shfl_xor(d, 32);
    if (g == 0) {
      const int gp = wid * 32 + m * 16 + r16;
      const float mu1v = a * (1.f / NF);
      s.murst[gp][0] = mu1v;
      s.murst[gp][1] = rsqrtf(v * (1.f / NF) - mu1v * mu1v + 1e-5f);
      const float mu2v = c * (1.f / NF);
      s.u2.murst2[gp][0] = mu2v;
      s.u2.murst2[gp][1] = rsqrtf(d * (1.f / NF) - mu2v * mu2v + 1e-5f);
    }
  }

  __syncthreads();   // A2: murst/murst2 visible

  // ---- phase 2: affine + bf16 staging of q/k/v from C-frags ----
  #pragma unroll
  for (int m = 0; m < 2; ++m) {
    const f32x4 aQV = m ? accQV1 : accQV0;
    const f32x4 aK  = m ? accK1  : accK0;
    #pragma unroll
    for (int j = 0; j < 4; ++j) {
      const int pix = wid * 32 + m * 16 + g * 4 + j;
      const float mu1v = s.murst[pix][0], rs1v = s.murst[pix][1];
      if (r16 < 8) {
        const float mu2v = s.u2.murst2[pix][0], rs2v = s.u2.murst2[pix][1];
        const float qv = (rs1v * (aQV[j] - mu1v * s.Sq1[r16]) + s.Sq0[r16]) * QS;
        s.qb16[pix * 8 + r16] = f2bf(qv);
        const float kv = rs2v * (aK[j] - mu2v * s.Sk1[r16]) + s.Sk0[r16];
        s.kb16[pix * 8 + r16] = f2bf(kv);
      } else {
        const float vv = rs1v * (aQV[j] - mu1v * s.Sv1[r16 - 8]) + s.Sv0[r16 - 8];
        s.vb16[r16 - 8][pix] = f2bf(vv);
      }
    }
  }

  __syncthreads();   // B: q/k/v staged; wb & murst2 regions now dead

  // ---- phase 3: MFMA attention: S^T = K·Q^T, P = exp2, O^T = V^T·P^T ----
  {
    const int qb0 = wid * 32;
    const short8v ones8 = {(short)0x3F80,(short)0x3F80,(short)0x3F80,(short)0x3F80,
                           (short)0x3F80,(short)0x3F80,(short)0x3F80,(short)0x3F80};

    short8v bq0 = zero8, bq1 = zero8;
    if (g == 0) {
      bq0 = *reinterpret_cast<const short8v*>(&s.qb16[(qb0 + r16) * 8]);
      bq1 = *reinterpret_cast<const short8v*>(&s.qb16[(qb0 + 16 + r16) * 8]);
    }

    f32x4 o0 = zero4, o1 = zero4;
    unsigned short* __restrict__ pst = &s.u2.pstage[wid][0];
    const int wr_off = r16 * 40 + g * 4;
    const int rd_off = r16 * 40 + g * 8;

    #pragma unroll 2
    for (int ch = 0; ch < 8; ++ch) {
      const int u0 = ch * 32;
      short8v ak0 = zero8, ak1 = zero8;
      if (g == 0) {
        ak0 = *reinterpret_cast<const short8v*>(&s.kb16[(u0 + r16) * 8]);
        ak1 = *reinterpret_cast<const short8v*>(&s.kb16[(u0 + 16 + r16) * 8]);
      }
      short8v av = zero8;
      if (r16 < 8)       av = *reinterpret_cast<const short8v*>(&s.vb16[r16][u0 + g * 8]);
      else if (r16 == 8) av = ones8;

      {
        f32x4 s0 = __builtin_amdgcn_mfma_f32_16x16x32_bf16(ak0, bq0, zero4, 0, 0, 0);
        f32x4 s1v = __builtin_amdgcn_mfma_f32_16x16x32_bf16(ak1, bq0, zero4, 0, 0, 0);
        const uint2 p0 = exp2_pack(s0);
        const uint2 p1 = exp2_pack(s1v);
        *reinterpret_cast<uint2*>(&pst[wr_off])      = p0;
        *reinterpret_cast<uint2*>(&pst[wr_off + 16]) = p1;
        const short8v bp = *reinterpret_cast<const short8v*>(&pst[rd_off]);
        o0 = __builtin_amdgcn_mfma_f32_16x16x32_bf16(av, bp, o0, 0, 0, 0);
      }
      {
        f32x4 s0 = __builtin_amdgcn_mfma_f32_16x16x32_bf16(ak0, bq1, zero4, 0, 0, 0);
        f32x4 s1v = __builtin_amdgcn_mfma_f32_16x16x32_bf16(ak1, bq1, zero4, 0, 0, 0);
        const uint2 p0 = exp2_pack(s0);
        const uint2 p1 = exp2_pack(s1v);
        *reinterpret_cast<uint2*>(&pst[wr_off])      = p0;
        *reinterpret_cast<uint2*>(&pst[wr_off + 16]) = p1;
        const short8v bp = *reinterpret_cast<const short8v*>(&pst[rd_off]);
        o1 = __builtin_amdgcn_mfma_f32_16x16x32_bf16(av, bp, o1, 0, 0, 0);
      }
    }

    {
      const int q0 = qb0 + r16;
      const int q1i = qb0 + 16 + r16;
      if (g == 0) {
        *reinterpret_cast<float2*>(&s.u1.mpst[q0][0]) = make_float2(o0.x, o0.y);
        *reinterpret_cast<float2*>(&s.u1.mpst[q0][2]) = make_float2(o0.z, o0.w);
        *reinterpret_cast<float2*>(&s.u1.mpst[q1i][0]) = make_float2(o1.x, o1.y);
        *reinterpret_cast<float2*>(&s.u1.mpst[q1i][2]) = make_float2(o1.z, o1.w);
      } else if (g == 1) {
        *reinterpret_cast<float2*>(&s.u1.mpst[q0][4]) = make_float2(o0.x, o0.y);
        *reinterpret_cast<float2*>(&s.u1.mpst[q0][6]) = make_float2(o0.z, o0.w);
        *reinterpret_cast<float2*>(&s.u1.mpst[q1i][4]) = make_float2(o1.x, o1.y);
        *reinterpret_cast<float2*>(&s.u1.mpst[q1i][6]) = make_float2(o1.z, o1.w);
      } else if (g == 2) {
        s.u1.mpst[q0][8] = o0.x;     // softmax denominator (ones-row)
        s.u1.mpst[q1i][8] = o1.x;
      }
    }
  }

  __syncthreads();   // C: O^T + l staged

  // ---- phase 4: softmax divide + bias-sel, fan-out + gated residual ----
  {
    const int qg = tid & 255;
    const int role = tid >> 8;
    const float rl = 1.0f / s.u1.mpst[qg][8];
    float mp[NH];
    #pragma unroll
    for (int d = 0; d < NH; d++) mp[d] = s.u1.mpst[qg][d] * rl + s.bsel[d];

    const float m1 = s.murst[qg][0];
    const float r1 = s.murst[qg][1];
    const int c0 = role * 32;
    const size_t qbase = rowbase + qg;
    const float* p = x1 + qbase;
    #pragma unroll 4
    for (int cc = 0; cc < 32; cc++) {
      const int c = c0 + cc;
      float fo = fan_b[c];
      #pragma unroll
      for (int d = 0; d < NH; d++) fo += mp[d] * fan_w[c * NH + d];
      const float xv  = p[(size_t)c * HW];
      const float x1n = (xv - m1) * r1 * ln1w[c] + ln1b[c];
      out[qbase + (size_t)c * HW] = x1n + gma[c] * fo;
    }
  }
}

extern "C" void kernel_launch(void* const* d_in, const int* in_sizes, int n_in,
                              void* d_out, int out_size, void* d_ws, size_t ws_size,
                              hipStream_t stream) {
  (void)in_sizes; (void)n_in; (void)d_ws; (void)ws_size; (void)out_size;
  const float* x1    = (const float*)d_in[0];
  const float* x2    = (const float*)d_in[1];
  const float* q_w   = (const float*)d_in[2];
  const float* q_b   = (const float*)d_in[3];
  const float* k_w   = (const float*)d_in[4];
  const float* k_b   = (const float*)d_in[5];
  const float* v_w   = (const float*)d_in[6];
  const float* v_b   = (const float*)d_in[7];
  const float* bias  = (const float*)d_in[8];
  const float* sel_w = (const float*)d_in[9];
  const float* sel_b = (const float*)d_in[10];
  const float* fan_w = (const float*)d_in[11];
  const float* fan_b = (const float*)d_in[12];
  const float* gma   = (const float*)d_in[13];
  const float* ln1w  = (const float*)d_in[14];
  const float* ln1b  = (const float*)d_in[15];
  const float* ln2w  = (const float*)d_in[16];
  const float* ln2b  = (const float*)d_in[17];

  hipLaunchKernelGGL(cc_attn_kernel, dim3(4 * HH), dim3(BDIM), 0, stream,
                     x1, x2, q_w, q_b, k_w, k_b, v_w, v_b, bias, sel_w, sel_b,
                     fan_w, fan_b, gma, ln1w, ln1b, ln2w, ln2b,
                     (float*)d_out);
}

// Round 8
// 73.576 us; speedup vs baseline: 1.7167x; 1.7167x over previous
//
#include <hip/hip_runtime.h>

#define BDIM 512
#define HH 256
#define WW 256
#define NF 64
#define NH 8
#define HW (HH * WW)
#define WBP 68   // padded weight row (bf16 elems)

typedef __attribute__((ext_vector_type(8))) short short8v;
typedef __attribute__((ext_vector_type(4))) float f32x4;

// round-to-nearest-even fp32 -> bf16 bits
__device__ __forceinline__ unsigned short f2bf(float f) {
  const unsigned u = __float_as_uint(f);
  return (unsigned short)((u + 0x7fffu + ((u >> 16) & 1u)) >> 16);
}

// exp2 of 4 fp32 -> packed 2x(2xbf16)
__device__ __forceinline__ uint2 exp2_pack(f32x4 sv) {
  const float e0 = __builtin_amdgcn_exp2f(sv.x);
  const float e1 = __builtin_amdgcn_exp2f(sv.y);
  const float e2 = __builtin_amdgcn_exp2f(sv.z);
  const float e3 = __builtin_amdgcn_exp2f(sv.w);
  uint2 r;
  r.x = (unsigned)f2bf(e0) | ((unsigned)f2bf(e1) << 16);
  r.y = (unsigned)f2bf(e2) | ((unsigned)f2bf(e3) << 16);
  return r;
}

struct __align__(16) Smem {
  unsigned short kb16[WW * 8];     // 4 KB   [u][d]  K bf16
  unsigned short qb16[WW * 8];     // 4 KB   [q][d]  Q bf16, pre-scaled
  unsigned short vb16[8][264];     // 4.125  [d][u]  V bf16 transposed
  union {                          // 10 KB
    struct { unsigned short wb1[16 * WBP]; unsigned short wb2[16 * WBP]; } w;
    float mpst[WW][10];            // [q][ d0..7, l, pad ]  (attention output)
  } u1;
  union {                          // 10 KB
    unsigned short pstage[8][640]; // per-wave P^T staging (attention)
    float murst2[WW][2];           // mu2, rstd2 (projection)
  } u2;
  float murst[WW][2];              // 2 KB  mu1, rstd1 (lives to epilogue)
  float Sq1[NH], Sq0[NH], Sk1[NH], Sk0[NH], Sv1[NH], Sv0[NH], bsel[NH];
};

__global__ __launch_bounds__(BDIM, 8)
void cc_attn_kernel(const float* __restrict__ x1,
                    const float* __restrict__ x2,
                    const float* __restrict__ q_w,
                    const float* __restrict__ q_b,
                    const float* __restrict__ k_w,
                    const float* __restrict__ k_b,
                    const float* __restrict__ v_w,
                    const float* __restrict__ v_b,
                    const float* __restrict__ bias,
                    const float* __restrict__ sel_w,
                    const float* __restrict__ sel_b,
                    const float* __restrict__ fan_w,
                    const float* __restrict__ fan_b,
                    const float* __restrict__ gma,
                    const float* __restrict__ ln1w,
                    const float* __restrict__ ln1b,
                    const float* __restrict__ ln2w,
                    const float* __restrict__ ln2b,
                    float* __restrict__ out)
{
  __shared__ Smem s;
  const int tid  = threadIdx.x;
  const int lane = tid & 63;
  const int wid  = tid >> 6;          // 8 waves
  const int g    = lane >> 4;         // k-octet / row-quad group
  const int r16  = lane & 15;
  const int b = blockIdx.x >> 8;
  const int h = blockIdx.x & 255;
  const size_t rowbase = ((size_t)(b * NF) * HH + h) * WW;

  const float QS = 0.125f * 1.44269504088896340736f;  // SCALE * log2(e)
  const short8v zero8 = {0,0,0,0,0,0,0,0};
  const f32x4 zero4 = {0.f, 0.f, 0.f, 0.f};

  // ---- phase 0a: per-head affine constants (threads 0..7) ----
  if (tid < NH) {
    const int d = tid;
    float s1q = 0, s0q = 0, s1k = 0, s0k = 0, s1v = 0, s0v = 0, bs = 0;
    for (int c = 0; c < NF; c++) {
      const float qw = q_w[d * NF + c], kw = k_w[d * NF + c], vw = v_w[d * NF + c];
      s1q += ln1w[c] * qw; s0q += ln1b[c] * qw;
      s1k += ln2w[c] * kw; s0k += ln2b[c] * kw;
      s1v += ln1w[c] * vw; s0v += ln1b[c] * vw;
      bs  += bias[c] * sel_w[d * NF + c];
    }
    s.Sq1[d] = s1q; s.Sq0[d] = s0q + q_b[d];
    s.Sk1[d] = s1k; s.Sk0[d] = s0k + k_b[d];
    s.Sv1[d] = s1v; s.Sv0[d] = s0v + v_b[d];
    s.bsel[d] = bs + sel_b[d];
  }

  // ---- phase 0b: LN-gain-folded weight matrices, bf16 [n][c] ----
  for (int i = tid; i < 16 * NF; i += BDIM) {
    const int n = i >> 6, c = i & 63;
    const float w1 = (n < 8 ? q_w[n * NF + c] : v_w[(n - 8) * NF + c]) * ln1w[c];
    const float w2 = (n < 8 ? k_w[n * NF + c] * ln2w[c] : 0.f);
    s.u1.w.wb1[n * WBP + c] = f2bf(w1);
    s.u1.w.wb2[n * WBP + c] = f2bf(w2);
  }

  __syncthreads();   // A: weights + consts visible

  // ---- phase 1: projection GEMMs via MFMA, two low-pressure passes ----
  f32x4 accQV0 = zero4, accQV1 = zero4;
  float s1[2] = {0.f, 0.f}, q1[2] = {0.f, 0.f};

  // pass A: x1 -> (Q|V) and LN1 stats
  #pragma unroll 1
  for (int kc = 0; kc < 2; ++kc) {
    const short8v bqv = *reinterpret_cast<const short8v*>(&s.u1.w.wb1[r16 * WBP + kc * 32 + g * 8]);
    #pragma unroll
    for (int m = 0; m < 2; ++m) {
      const int gp = wid * 32 + m * 16 + r16;
      const float* p1 = x1 + rowbase + gp + (size_t)(kc * 32 + g * 8) * HW;
      float xv[8];
      #pragma unroll
      for (int i = 0; i < 8; ++i) xv[i] = p1[(size_t)i * HW];
      unsigned short pk1[8];
      float la = 0.f, lb = 0.f;
      #pragma unroll
      for (int i = 0; i < 8; ++i) { la += xv[i]; lb += xv[i] * xv[i]; pk1[i] = f2bf(xv[i]); }
      s1[m] += la; q1[m] += lb;
      const short8v a1 = *reinterpret_cast<const short8v*>(pk1);
      if (m == 0) accQV0 = __builtin_amdgcn_mfma_f32_16x16x32_bf16(a1, bqv, accQV0, 0, 0, 0);
      else        accQV1 = __builtin_amdgcn_mfma_f32_16x16x32_bf16(a1, bqv, accQV1, 0, 0, 0);
    }
  }

  // pass B: x2 -> K and LN2 stats
  f32x4 accK0 = zero4, accK1 = zero4;
  float s2[2] = {0.f, 0.f}, q2p[2] = {0.f, 0.f};
  #pragma unroll 1
  for (int kc = 0; kc < 2; ++kc) {
    const short8v bk = *reinterpret_cast<const short8v*>(&s.u1.w.wb2[r16 * WBP + kc * 32 + g * 8]);
    #pragma unroll
    for (int m = 0; m < 2; ++m) {
      const int gp = wid * 32 + m * 16 + r16;
      const float* p2 = x2 + rowbase + gp + (size_t)(kc * 32 + g * 8) * HW;
      float yv[8];
      #pragma unroll
      for (int i = 0; i < 8; ++i) yv[i] = p2[(size_t)i * HW];
      unsigned short pk2[8];
      float lc = 0.f, ld = 0.f;
      #pragma unroll
      for (int i = 0; i < 8; ++i) { lc += yv[i]; ld += yv[i] * yv[i]; pk2[i] = f2bf(yv[i]); }
      s2[m] += lc; q2p[m] += ld;
      const short8v a2 = *reinterpret_cast<const short8v*>(pk2);
      if (m == 0) accK0 = __builtin_amdgcn_mfma_f32_16x16x32_bf16(a2, bk, accK0, 0, 0, 0);
      else        accK1 = __builtin_amdgcn_mfma_f32_16x16x32_bf16(a2, bk, accK1, 0, 0, 0);
    }
  }

  // ---- phase 1b: LN stats combine (lane pairs hold complementary octets) ----
  #pragma unroll
  for (int m = 0; m < 2; ++m) {
    float a = s1[m] + __shfl_xor(s1[m], 16);   a += __shfl_xor(a, 32);
    float v = q1[m] + __shfl_xor(q1[m], 16);   v += __shfl_xor(v, 32);
    float c = s2[m] + __shfl_xor(s2[m], 16);   c += __shfl_xor(c, 32);
    float d = q2p[m] + __shfl_xor(q2p[m], 16); d += __shfl_xor(d, 32);
    if (g == 0) {
      const int gp = wid * 32 + m * 16 + r16;
      const float mu1v = a * (1.f / NF);
      s.murst[gp][0] = mu1v;
      s.murst[gp][1] = rsqrtf(v * (1.f / NF) - mu1v * mu1v + 1e-5f);
      const float mu2v = c * (1.f / NF);
      s.u2.murst2[gp][0] = mu2v;
      s.u2.murst2[gp][1] = rsqrtf(d * (1.f / NF) - mu2v * mu2v + 1e-5f);
    }
  }

  __syncthreads();   // A2: murst/murst2 visible

  // ---- phase 2: affine + bf16 staging of q/k/v from C-frags ----
  #pragma unroll
  for (int m = 0; m < 2; ++m) {
    const f32x4 aQV = m ? accQV1 : accQV0;
    const f32x4 aK  = m ? accK1  : accK0;
    #pragma unroll
    for (int j = 0; j < 4; ++j) {
      const int pix = wid * 32 + m * 16 + g * 4 + j;
      const float mu1v = s.murst[pix][0], rs1v = s.murst[pix][1];
      if (r16 < 8) {
        const float mu2v = s.u2.murst2[pix][0], rs2v = s.u2.murst2[pix][1];
        const float qv = (rs1v * (aQV[j] - mu1v * s.Sq1[r16]) + s.Sq0[r16]) * QS;
        s.qb16[pix * 8 + r16] = f2bf(qv);
        const float kv = rs2v * (aK[j] - mu2v * s.Sk1[r16]) + s.Sk0[r16];
        s.kb16[pix * 8 + r16] = f2bf(kv);
      } else {
        const float vv = rs1v * (aQV[j] - mu1v * s.Sv1[r16 - 8]) + s.Sv0[r16 - 8];
        s.vb16[r16 - 8][pix] = f2bf(vv);
      }
    }
  }

  __syncthreads();   // B: q/k/v staged; wb & murst2 regions now dead

  // ---- phase 3: MFMA attention: S^T = K·Q^T, P = exp2, O^T = V^T·P^T ----
  {
    const int qb0 = wid * 32;
    const short8v ones8 = {(short)0x3F80,(short)0x3F80,(short)0x3F80,(short)0x3F80,
                           (short)0x3F80,(short)0x3F80,(short)0x3F80,(short)0x3F80};

    short8v bq0 = zero8, bq1 = zero8;
    if (g == 0) {
      bq0 = *reinterpret_cast<const short8v*>(&s.qb16[(qb0 + r16) * 8]);
      bq1 = *reinterpret_cast<const short8v*>(&s.qb16[(qb0 + 16 + r16) * 8]);
    }

    f32x4 o0 = zero4, o1 = zero4;
    unsigned short* __restrict__ pst = &s.u2.pstage[wid][0];
    const int wr_off = r16 * 40 + g * 4;
    const int rd_off = r16 * 40 + g * 8;

    #pragma unroll 2
    for (int ch = 0; ch < 8; ++ch) {
      const int u0 = ch * 32;
      short8v ak0 = zero8, ak1 = zero8;
      if (g == 0) {
        ak0 = *reinterpret_cast<const short8v*>(&s.kb16[(u0 + r16) * 8]);
        ak1 = *reinterpret_cast<const short8v*>(&s.kb16[(u0 + 16 + r16) * 8]);
      }
      short8v av = zero8;
      if (r16 < 8)       av = *reinterpret_cast<const short8v*>(&s.vb16[r16][u0 + g * 8]);
      else if (r16 == 8) av = ones8;

      {
        f32x4 s0 = __builtin_amdgcn_mfma_f32_16x16x32_bf16(ak0, bq0, zero4, 0, 0, 0);
        f32x4 s1v = __builtin_amdgcn_mfma_f32_16x16x32_bf16(ak1, bq0, zero4, 0, 0, 0);
        const uint2 p0 = exp2_pack(s0);
        const uint2 p1 = exp2_pack(s1v);
        *reinterpret_cast<uint2*>(&pst[wr_off])      = p0;
        *reinterpret_cast<uint2*>(&pst[wr_off + 16]) = p1;
        const short8v bp = *reinterpret_cast<const short8v*>(&pst[rd_off]);
        o0 = __builtin_amdgcn_mfma_f32_16x16x32_bf16(av, bp, o0, 0, 0, 0);
      }
      {
        f32x4 s0 = __builtin_amdgcn_mfma_f32_16x16x32_bf16(ak0, bq1, zero4, 0, 0, 0);
        f32x4 s1v = __builtin_amdgcn_mfma_f32_16x16x32_bf16(ak1, bq1, zero4, 0, 0, 0);
        const uint2 p0 = exp2_pack(s0);
        const uint2 p1 = exp2_pack(s1v);
        *reinterpret_cast<uint2*>(&pst[wr_off])      = p0;
        *reinterpret_cast<uint2*>(&pst[wr_off + 16]) = p1;
        const short8v bp = *reinterpret_cast<const short8v*>(&pst[rd_off]);
        o1 = __builtin_amdgcn_mfma_f32_16x16x32_bf16(av, bp, o1, 0, 0, 0);
      }
    }

    {
      const int q0 = qb0 + r16;
      const int q1i = qb0 + 16 + r16;
      if (g == 0) {
        *reinterpret_cast<float2*>(&s.u1.mpst[q0][0]) = make_float2(o0.x, o0.y);
        *reinterpret_cast<float2*>(&s.u1.mpst[q0][2]) = make_float2(o0.z, o0.w);
        *reinterpret_cast<float2*>(&s.u1.mpst[q1i][0]) = make_float2(o1.x, o1.y);
        *reinterpret_cast<float2*>(&s.u1.mpst[q1i][2]) = make_float2(o1.z, o1.w);
      } else if (g == 1) {
        *reinterpret_cast<float2*>(&s.u1.mpst[q0][4]) = make_float2(o0.x, o0.y);
        *reinterpret_cast<float2*>(&s.u1.mpst[q0][6]) = make_float2(o0.z, o0.w);
        *reinterpret_cast<float2*>(&s.u1.mpst[q1i][4]) = make_float2(o1.x, o1.y);
        *reinterpret_cast<float2*>(&s.u1.mpst[q1i][6]) = make_float2(o1.z, o1.w);
      } else if (g == 2) {
        s.u1.mpst[q0][8] = o0.x;     // softmax denominator (ones-row)
        s.u1.mpst[q1i][8] = o1.x;
      }
    }
  }

  __syncthreads();   // C: O^T + l staged

  // ---- phase 4: softmax divide + bias-sel, fan-out + gated residual ----
  {
    const int qg = tid & 255;
    const int role = tid >> 8;
    const float rl = 1.0f / s.u1.mpst[qg][8];
    float mp[NH];
    #pragma unroll
    for (int d = 0; d < NH; d++) mp[d] = s.u1.mpst[qg][d] * rl + s.bsel[d];

    const float m1 = s.murst[qg][0];
    const float r1 = s.murst[qg][1];
    const int c0 = role * 32;
    const size_t qbase = rowbase + qg;
    const float* p = x1 + qbase;
    #pragma unroll 4
    for (int cc = 0; cc < 32; cc++) {
      const int c = c0 + cc;
      float fo = fan_b[c];
      #pragma unroll
      for (int d = 0; d < NH; d++) fo += mp[d] * fan_w[c * NH + d];
      const float xv  = p[(size_t)c * HW];
      const float x1n = (xv - m1) * r1 * ln1w[c] + ln1b[c];
      out[qbase + (size_t)c * HW] = x1n + gma[c] * fo;
    }
  }
}

extern "C" void kernel_launch(void* const* d_in, const int* in_sizes, int n_in,
                              void* d_out, int out_size, void* d_ws, size_t ws_size,
                              hipStream_t stream) {
  (void)in_sizes; (void)n_in; (void)d_ws; (void)ws_size; (void)out_size;
  const float* x1    = (const float*)d_in[0];
  const float* x2    = (const float*)d_in[1];
  const float* q_w   = (const float*)d_in[2];
  const float* q_b   = (const float*)d_in[3];
  const float* k_w   = (const float*)d_in[4];
  const float* k_b   = (const float*)d_in[5];
  const float* v_w   = (const float*)d_in[6];
  const float* v_b   = (const float*)d_in[7];
  const float* bias  = (const float*)d_in[8];
  const float* sel_w = (const float*)d_in[9];
  const float* sel_b = (const float*)d_in[10];
  const float* fan_w = (const float*)d_in[11];
  const float* fan_b = (const float*)d_in[12];
  const float* gma   = (const float*)d_in[13];
  const float* ln1w  = (const float*)d_in[14];
  const float* ln1b  = (const float*)d_in[15];
  const float* ln2w  = (const float*)d_in[16];
  const float* ln2b  = (const float*)d_in[17];

  hipLaunchKernelGGL(cc_attn_kernel, dim3(4 * HH), dim3(BDIM), 0, stream,
                     x1, x2, q_w, q_b, k_w, k_b, v_w, v_b, bias, sel_w, sel_b,
                     fan_w, fan_b, gma, ln1w, ln1b, ln2w, ln2b,
                     (float*)d_out);
}